// Round 2
// baseline (303.785 us; speedup 1.0000x reference)
//
#include <hip/hip_runtime.h>
#include <cstdint>
#include <cstddef>

// VanillaRNN: B=4096, T=512, H=128, C=10
// Round 2 design:
//  - 256 blocks x 256 threads (4 waves). Block owns 16 batch columns; wave w
//    owns hidden rows [32w, 32w+32) = two 16x16 MFMA M-tiles.
//  - Heavy steps: f16 two-limb (Ootomo) MFMA: W = W1 + 2^-11 W2', h = h1 +
//    2^-11 h2' (second limbs pre-scaled x2048, separate fp32 accumulator).
//    3 products/tile/kc -> per-step error ~1e-6, below fp32 op-order noise.
//    This fixes round 1's marginal-column sign flip (bf16 error ~2e-2 flipped
//    a column across the consensus-dynamics separatrix -> absmax 132 = 2*66).
//  - Light steps: once h freezes exactly (all columns saturated to +-1.0f;
//    tanh returns exact +-1.0f for |pre|>10), W.h is constant -> reuse accWh,
//    skip MFMA + LDS h-traffic. Per-wave change flags in double-buffered LDS
//    slots (read [t&1], write [(t+1)&1]: no same-step read/write race).
//    Expected ~10-20 heavy steps, rest light.

#define TLEN 512
#define HDIM 128
#define NCLS 10
#define HS   136                   // h column stride in f16 (272 B, 16B-aligned)
#define XS   132                   // x stage row stride in floats
#define LIMBSTRIDE (16 * HS)       // 2176 f16 per limb plane
#define PARSTRIDE  (2 * LIMBSTRIDE)

typedef _Float16 f16x8 __attribute__((ext_vector_type(8)));
typedef float    f32x4 __attribute__((ext_vector_type(4)));

union PK4 { _Float16 h[4]; uint2 u; };

__global__ __launch_bounds__(256, 1) void rnn_kernel(
    const float* __restrict__ x,    // [B,T]
    const float* __restrict__ Whx,  // [H]
    const float* __restrict__ Whh,  // [H,H]
    const float* __restrict__ Wph,  // [C,H]
    const float* __restrict__ bh,   // [H]
    const float* __restrict__ bp,   // [C]
    float* __restrict__ out)        // [B,C]
{
    __shared__ _Float16 hbuf[2 * PARSTRIDE];        // [parity][limb][col][k]
    __shared__ float    xs[16 * XS];                // [col][t_local]
    __shared__ int      slots[2][4] __attribute__((aligned(16)));

    const int tid  = threadIdx.x;
    const int w    = tid >> 6;     // wave 0..3: rows [32w, 32w+32)
    const int lane = tid & 63;
    const int n    = lane & 15;    // MFMA col (batch) / A-operand m
    const int q    = lane >> 4;    // quad
    const int blk  = blockIdx.x;

    // ---- W fragments, two f16 limbs (A[m=lane&15][k=8q+j] per 32-k chunk) ----
    f16x8 w1[2][4], w2[2][4];
    #pragma unroll
    for (int u = 0; u < 2; ++u) {
        #pragma unroll
        for (int kc = 0; kc < 4; ++kc) {
            const int row = 32 * w + 16 * u + n;
            const float* wp = &Whh[row * HDIM + 32 * kc + 8 * q];
            #pragma unroll
            for (int j = 0; j < 8; ++j) {
                const float v = wp[j];
                const _Float16 a = (_Float16)v;
                w1[u][kc][j] = a;
                w2[u][kc][j] = (_Float16)((v - (float)a) * 2048.0f);
            }
        }
    }
    // per-lane row constants: acc element (u,r) -> row 32w + 16u + 4q + r
    float wx[8], bb[8];
    #pragma unroll
    for (int u = 0; u < 2; ++u)
        #pragma unroll
        for (int r = 0; r < 4; ++r) {
            const int row = 32 * w + 16 * u + 4 * q + r;
            wx[4 * u + r] = Whx[row];
            bb[4 * u + r] = bh[row];
        }

    // h_0 = 0 in both parities; slots[0] forces heavy at t=0
    for (int i = tid; i < 2 * PARSTRIDE; i += 256) hbuf[i] = (_Float16)0.0f;
    if (tid < 4) { slots[0][tid] = 1; slots[1][tid] = 0; }

    float accWh[8], h_prev[8], hv[8];
    #pragma unroll
    for (int i = 0; i < 8; ++i) { accWh[i] = 0.0f; h_prev[i] = 0.0f; }
    int p = 0;  // parity of buffer holding current h (valid whenever read)

    auto writeLimbs = [&](int par) {
        #pragma unroll
        for (int u = 0; u < 2; ++u) {
            PK4 p1, p2;
            #pragma unroll
            for (int r = 0; r < 4; ++r) {
                const float v = hv[4 * u + r];
                const _Float16 hh = (_Float16)v;
                p1.h[r] = hh;
                p2.h[r] = (_Float16)((v - (float)hh) * 2048.0f);
            }
            const int kb = 32 * w + 16 * u + 4 * q;
            *(uint2*)&hbuf[par * PARSTRIDE +              n * HS + kb] = p1.u;
            *(uint2*)&hbuf[par * PARSTRIDE + LIMBSTRIDE + n * HS + kb] = p2.u;
        }
    };

    for (int t = 0; t < TLEN; ++t) {
        if ((t & 127) == 0) {
            const int xrow = tid >> 4, xo = (tid & 15) << 2;
            const float* xg = &x[(size_t)(blk * 16 + xrow) * TLEN + t];
            *(float4*)&xs[xrow * XS + xo]      = *(const float4*)&xg[xo];
            *(float4*)&xs[xrow * XS + xo + 64] = *(const float4*)&xg[xo + 64];
            __syncthreads();   // also covers hbuf/slots init at t=0
        }

        const int4 sv = *(const int4*)&slots[t & 1][0];
        const bool heavy = (sv.x | sv.y | sv.z | sv.w) != 0;  // h_t != h_{t-1}
        const float xt = xs[n * XS + (t & 127)];

        if (heavy) {
            const _Float16* hb = &hbuf[p * PARSTRIDE];
            f16x8 b1[4], b2[4];
            #pragma unroll
            for (int kc = 0; kc < 4; ++kc) {
                b1[kc] = *(const f16x8*)&hb[             n * HS + 32 * kc + 8 * q];
                b2[kc] = *(const f16x8*)&hb[LIMBSTRIDE + n * HS + 32 * kc + 8 * q];
            }
            #pragma unroll
            for (int u = 0; u < 2; ++u) {
                f32x4 a0 = {0.0f, 0.0f, 0.0f, 0.0f};
                f32x4 a1 = {0.0f, 0.0f, 0.0f, 0.0f};
                #pragma unroll
                for (int kc = 0; kc < 4; ++kc) {
                    a0 = __builtin_amdgcn_mfma_f32_16x16x32_f16(w1[u][kc], b1[kc], a0, 0, 0, 0);
                    a1 = __builtin_amdgcn_mfma_f32_16x16x32_f16(w1[u][kc], b2[kc], a1, 0, 0, 0);
                    a1 = __builtin_amdgcn_mfma_f32_16x16x32_f16(w2[u][kc], b1[kc], a1, 0, 0, 0);
                }
                #pragma unroll
                for (int r = 0; r < 4; ++r)
                    accWh[4 * u + r] = fmaf(a1[r], 0x1p-11f, a0[r]);
            }
        }

        float pre[8];
        #pragma unroll
        for (int i = 0; i < 8; ++i)
            pre[i] = accWh[i] + fmaf(wx[i], xt, bb[i]);

        bool sat = true;
        #pragma unroll
        for (int i = 0; i < 8; ++i) sat = sat && (fabsf(pre[i]) > 10.0f);
        if (__ballot(sat) == ~0ull) {
            // tanh(|pre|>10) == +-1.0f exactly; matches tanhf bit-for-bit
            #pragma unroll
            for (int i = 0; i < 8; ++i) hv[i] = copysignf(1.0f, pre[i]);
        } else {
            #pragma unroll
            for (int i = 0; i < 8; ++i) hv[i] = tanhf(pre[i]);
        }

        bool eq = true;
        #pragma unroll
        for (int i = 0; i < 8; ++i) eq = eq && (hv[i] == h_prev[i]);
        const bool wave_changed = (__ballot(eq) != ~0ull);
        #pragma unroll
        for (int i = 0; i < 8; ++i) h_prev[i] = hv[i];

        if (heavy) {
            writeLimbs(p ^ 1);   // full h_{t+1}; safe: reads were from buf[p]
            p ^= 1;
        } else if (wave_changed) {
            // light mode => both buffers hold current h (synced invariant);
            // nobody reads buffers this step -> writing both keeps them synced
            writeLimbs(0);
            writeLimbs(1);
        }
        if (lane == 0) slots[(t + 1) & 1][w] = wave_changed ? 1 : 0;
        __syncthreads();
    }

    // ---- projection: out[b][co] = sum_i Wph[co][i]*h_T[i][b] + bp[co] ----
    if (tid < 16 * NCLS) {
        const int c  = tid / NCLS;
        const int co = tid - c * NCLS;
        const _Float16* h1 = &hbuf[p * PARSTRIDE +              c * HS];
        const _Float16* h2 = &hbuf[p * PARSTRIDE + LIMBSTRIDE + c * HS];
        float s = bp[co];
        #pragma unroll 8
        for (int i = 0; i < HDIM; ++i)
            s = fmaf(Wph[co * HDIM + i],
                     (float)h1[i] + (float)h2[i] * (1.0f / 2048.0f), s);
        out[((size_t)blk * 16 + c) * NCLS + co] = s;
    }
}

extern "C" void kernel_launch(void* const* d_in, const int* in_sizes, int n_in,
                              void* d_out, int out_size, void* d_ws, size_t ws_size,
                              hipStream_t stream) {
    const float* x   = (const float*)d_in[0];  // [4096,512]
    const float* Whx = (const float*)d_in[1];  // [128,1]
    const float* Whh = (const float*)d_in[2];  // [128,128]
    const float* Wph = (const float*)d_in[3];  // [10,128]
    const float* bh  = (const float*)d_in[4];  // [128,1]
    const float* bp  = (const float*)d_in[5];  // [10,1]
    float* out = (float*)d_out;                // [4096,10]

    rnn_kernel<<<dim3(256), dim3(256), 0, stream>>>(x, Whx, Whh, Wph, bh, bp, out);
}

// Round 3
// 86.192 us; speedup vs baseline: 3.5245x; 3.5245x over previous
//
#include <hip/hip_runtime.h>
#include <cstdint>
#include <cstddef>

// VanillaRNN: B=4096, T=512, H=128, C=10
// Round 3: round 2 (two-limb f16 MFMA heavy steps + saturation lock) PLUS
// time-skip: once the block is stable (h == h_prev, all |pre|>10 => h=+-1
// exactly, accWh registers current), a step is the identity iff
// |x_t[b]| < X_b,  X_b = min_i (c_i*h_i - 10.5)/|Whx_i|,  c = accWh + bh
// (margin => |pre|>10.4, sign unchanged => ballot-all-sat path gives
// copysign == h_prev, bit-identical to executing the step). Scan x for the
// first violating t; jump there (or to T). Removes ~500 barrier-bound steps.
// Round 2 measured MfmaUtil=0.26% (=> ~5-10 heavy steps), VALUBusy=19%,
// 251us: pure per-step latency. Executed-step numerics kept bit-identical.

#define TLEN 512
#define HDIM 128
#define NCLS 10
#define HS   136                   // h column stride in f16 (272 B, 16B-aligned)
#define LIMBSTRIDE (16 * HS)
#define PARSTRIDE  (2 * LIMBSTRIDE)

typedef _Float16 f16x8 __attribute__((ext_vector_type(8)));
typedef float    f32x4 __attribute__((ext_vector_type(4)));

union PK4 { _Float16 h[4]; uint2 u; };

__global__ __launch_bounds__(256, 1) void rnn_kernel(
    const float* __restrict__ x,    // [B,T]
    const float* __restrict__ Whx,  // [H]
    const float* __restrict__ Whh,  // [H,H]
    const float* __restrict__ Wph,  // [C,H]
    const float* __restrict__ bh,   // [H]
    const float* __restrict__ bp,   // [C]
    float* __restrict__ out)        // [B,C]
{
    __shared__ _Float16 hbuf[2 * PARSTRIDE];   // [parity][limb][col][k]
    __shared__ int      slots[2][4] __attribute__((aligned(16)));
    __shared__ int      satf [2][4] __attribute__((aligned(16)));
    __shared__ unsigned Xs[16];
    __shared__ int      tmin;

    const int tid  = threadIdx.x;
    const int w    = tid >> 6;     // wave 0..3: rows [32w, 32w+32)
    const int lane = tid & 63;
    const int n    = lane & 15;    // MFMA col (batch)
    const int q    = lane >> 4;    // quad
    const int blk  = blockIdx.x;

    // ---- W_hh fragments, two f16 limbs: A[m=lane&15][k=8q+j] per 32-k chunk ----
    f16x8 w1[2][4], w2[2][4];
    #pragma unroll
    for (int u = 0; u < 2; ++u) {
        #pragma unroll
        for (int kc = 0; kc < 4; ++kc) {
            const int row = 32 * w + 16 * u + n;
            const float* wp = &Whh[row * HDIM + 32 * kc + 8 * q];
            #pragma unroll
            for (int j = 0; j < 8; ++j) {
                const float v = wp[j];
                const _Float16 a = (_Float16)v;
                w1[u][kc][j] = a;
                w2[u][kc][j] = (_Float16)((v - (float)a) * 2048.0f);
            }
        }
    }
    // per-lane row constants: acc element (u,r) -> row 32w + 16u + 4q + r
    float wx[8], bb[8];
    #pragma unroll
    for (int u = 0; u < 2; ++u)
        #pragma unroll
        for (int r = 0; r < 4; ++r) {
            const int row = 32 * w + 16 * u + 4 * q + r;
            wx[4 * u + r] = Whx[row];
            bb[4 * u + r] = bh[row];
        }

    for (int i = tid; i < 2 * PARSTRIDE; i += 256) hbuf[i] = (_Float16)0.0f;
    if (tid < 4) { slots[0][tid] = 1; slots[1][tid] = 0;
                   satf[0][tid] = 0;  satf[1][tid] = 0; }
    __syncthreads();

    float accWh[8], h_prev[8], hv[8];
    #pragma unroll
    for (int i = 0; i < 8; ++i) { accWh[i] = 0.0f; h_prev[i] = 0.0f; }
    int p = 0;                     // parity of buffer holding current h
    bool force_step = false;

    const float* xcol = &x[(size_t)(blk * 16 + n) * TLEN];

    auto writeLimbs = [&](int par) {
        #pragma unroll
        for (int u = 0; u < 2; ++u) {
            PK4 p1, p2;
            #pragma unroll
            for (int r = 0; r < 4; ++r) {
                const float v = hv[4 * u + r];
                const _Float16 hh = (_Float16)v;
                p1.h[r] = hh;
                p2.h[r] = (_Float16)((v - (float)hh) * 2048.0f);
            }
            const int kb = 32 * w + 16 * u + 4 * q;
            *(uint2*)&hbuf[par * PARSTRIDE +              n * HS + kb] = p1.u;
            *(uint2*)&hbuf[par * PARSTRIDE + LIMBSTRIDE + n * HS + kb] = p2.u;
        }
    };

    int t = 0;
    while (t < TLEN) {
        const int4 sv = *(const int4*)&slots[t & 1][0];
        const int4 ss = *(const int4*)&satf[t & 1][0];
        const bool heavy  = (sv.x | sv.y | sv.z | sv.w) != 0;
        const bool allsat = (ss.x & ss.y & ss.z & ss.w) != 0;

        if (!force_step && !heavy && allsat) {
            // ---- stable: h frozen at exact +-1, accWh current. Scan ahead. ----
            if (tid < 16) Xs[tid] = 0x7f800000u;                  // +inf bits
            if (tid < 4)  { slots[0][tid] = 0; slots[1][tid] = 0; }
            if (tid == 0) tmin = TLEN;
            float m8 = 3.0e38f;
            #pragma unroll
            for (int i = 0; i < 8; ++i) {
                const float c  = accWh[i] + bb[i];
                const float mi = (c * h_prev[i] - 10.5f) / fmaxf(fabsf(wx[i]), 1e-30f);
                m8 = fminf(m8, mi);
            }
            m8 = fmaxf(m8, 0.0f);                                 // nonneg: uint order ok
            __syncthreads();
            atomicMin(&Xs[n], __float_as_uint(m8));
            __syncthreads();
            const int   row = tid >> 4;
            const float Xc  = __uint_as_float(Xs[row]);
            const float* xp = &x[(size_t)(blk * 16 + row) * TLEN];
            for (int tt = t + (tid & 15); tt < TLEN; tt += 16) {
                if (fabsf(xp[tt]) >= Xc) { atomicMin(&tmin, tt); break; }
            }
            __syncthreads();
            const int tv = tmin;
            if (tv >= TLEN) { t = TLEN; break; }   // identity to the end
            t = tv;                                // steps [t, tv) are identity
            force_step = true;                     // run a real (light) step at tv
            continue;
        }
        force_step = false;

        const float xt = xcol[t];

        if (heavy) {
            const _Float16* hb = &hbuf[p * PARSTRIDE];
            f16x8 b1[4], b2[4];
            #pragma unroll
            for (int kc = 0; kc < 4; ++kc) {
                b1[kc] = *(const f16x8*)&hb[             n * HS + 32 * kc + 8 * q];
                b2[kc] = *(const f16x8*)&hb[LIMBSTRIDE + n * HS + 32 * kc + 8 * q];
            }
            #pragma unroll
            for (int u = 0; u < 2; ++u) {
                f32x4 a0 = {0.0f, 0.0f, 0.0f, 0.0f};
                f32x4 a1 = {0.0f, 0.0f, 0.0f, 0.0f};
                #pragma unroll
                for (int kc = 0; kc < 4; ++kc) {
                    a0 = __builtin_amdgcn_mfma_f32_16x16x32_f16(w1[u][kc], b1[kc], a0, 0, 0, 0);
                    a1 = __builtin_amdgcn_mfma_f32_16x16x32_f16(w1[u][kc], b2[kc], a1, 0, 0, 0);
                    a1 = __builtin_amdgcn_mfma_f32_16x16x32_f16(w2[u][kc], b1[kc], a1, 0, 0, 0);
                }
                #pragma unroll
                for (int r = 0; r < 4; ++r)
                    accWh[4 * u + r] = fmaf(a1[r], 0x1p-11f, a0[r]);
            }
        }

        float pre[8];
        #pragma unroll
        for (int i = 0; i < 8; ++i)
            pre[i] = accWh[i] + fmaf(wx[i], xt, bb[i]);

        bool sat = true;
        #pragma unroll
        for (int i = 0; i < 8; ++i) sat = sat && (fabsf(pre[i]) > 10.0f);
        const bool wave_sat = (__ballot(sat) == ~0ull);
        if (wave_sat) {
            #pragma unroll
            for (int i = 0; i < 8; ++i) hv[i] = copysignf(1.0f, pre[i]);
        } else {
            #pragma unroll
            for (int i = 0; i < 8; ++i) hv[i] = tanhf(pre[i]);
        }

        bool eq = true;
        #pragma unroll
        for (int i = 0; i < 8; ++i) eq = eq && (hv[i] == h_prev[i]);
        const bool wave_changed = (__ballot(eq) != ~0ull);
        #pragma unroll
        for (int i = 0; i < 8; ++i) h_prev[i] = hv[i];

        if (heavy) {
            writeLimbs(p ^ 1);
            p ^= 1;
        } else if (wave_changed) {
            writeLimbs(0);                 // keep both parities current
            writeLimbs(1);
        }
        if (lane == 0) {
            slots[(t + 1) & 1][w] = wave_changed ? 1 : 0;
            satf [(t + 1) & 1][w] = wave_sat ? 1 : 0;
        }
        __syncthreads();
        ++t;
    }

    // ---- projection: out[b][co] = sum_i Wph[co][i]*h_T[i][b] + bp[co] ----
    if (tid < 16 * NCLS) {
        const int c  = tid / NCLS;
        const int co = tid - c * NCLS;
        const _Float16* h1 = &hbuf[p * PARSTRIDE +              c * HS];
        const _Float16* h2 = &hbuf[p * PARSTRIDE + LIMBSTRIDE + c * HS];
        float s = bp[co];
        #pragma unroll 8
        for (int i = 0; i < HDIM; ++i)
            s = fmaf(Wph[co * HDIM + i],
                     (float)h1[i] + (float)h2[i] * (1.0f / 2048.0f), s);
        out[((size_t)blk * 16 + c) * NCLS + co] = s;
    }
}

extern "C" void kernel_launch(void* const* d_in, const int* in_sizes, int n_in,
                              void* d_out, int out_size, void* d_ws, size_t ws_size,
                              hipStream_t stream) {
    const float* x   = (const float*)d_in[0];  // [4096,512]
    const float* Whx = (const float*)d_in[1];  // [128,1]
    const float* Whh = (const float*)d_in[2];  // [128,128]
    const float* Wph = (const float*)d_in[3];  // [10,128]
    const float* bh  = (const float*)d_in[4];  // [128,1]
    const float* bp  = (const float*)d_in[5];  // [10,1]
    float* out = (float*)d_out;                // [4096,10]

    rnn_kernel<<<dim3(256), dim3(256), 0, stream>>>(x, Whx, Whh, Wph, bh, bp, out);
}

// Round 4
// 79.612 us; speedup vs baseline: 3.8158x; 1.0827x over previous
//
#include <hip/hip_runtime.h>
#include <cstdint>
#include <cstddef>

// VanillaRNN: B=4096, T=512, H=128, C=10
// Round 4: round-3 structure (two-limb f16 MFMA heavy steps + saturation
// lock + time-skip) with the serialized x-scan removed:
//  - x prefetched into registers at kernel start (8 x float4 per thread,
//    independent loads -> pipelined; warms L1/L2 for step-path reads).
//  - stable-time scan is a branchless unrolled compare/select over the
//    register copy (round 3 scanned global memory with a data-dependent
//    early-exit branch: up to 32 serialized ~900-cyc HBM-latency loads
//    per thread ~= 12 us).
//  - tanhf -> __expf-based tanh on the ~8 pre-lock steps (err ~3e-7 abs,
//    4 orders below the bf16 error that flipped a column in round 1;
//    saturates to exact +-1.0f for |x|>10, consistent with copysign path).
// Skip-step validity: stable (h==h_prev, all |pre|>10 => h=+-1 exact, accWh
// current) => step t is identity iff |x_t[b]| < X_b,
// X_b = min_i (c_i h_i - 10.5)/|Whx_i|, c = accWh + bh (margin => |pre|>10.4,
// sign unchanged => ballot-all-sat path returns copysign == h_prev).

#define TLEN 512
#define HDIM 128
#define NCLS 10
#define HS   136                   // h column stride in f16 (272 B, 16B-aligned)
#define LIMBSTRIDE (16 * HS)
#define PARSTRIDE  (2 * LIMBSTRIDE)

typedef _Float16 f16x8 __attribute__((ext_vector_type(8)));
typedef float    f32x4 __attribute__((ext_vector_type(4)));

union PK4 { _Float16 h[4]; uint2 u; };

__device__ __forceinline__ float tanh_fast(float x) {
    // tanh(x) = 1 - 2/(e^{2x}+1); exact +-1.0f for |x|>10 after fp32 rounding
    float e = __expf(2.0f * x);
    return 1.0f - 2.0f * __builtin_amdgcn_rcpf(e + 1.0f);
}

__global__ __launch_bounds__(256, 1) void rnn_kernel(
    const float* __restrict__ x,    // [B,T]
    const float* __restrict__ Whx,  // [H]
    const float* __restrict__ Whh,  // [H,H]
    const float* __restrict__ Wph,  // [C,H]
    const float* __restrict__ bh,   // [H]
    const float* __restrict__ bp,   // [C]
    float* __restrict__ out)        // [B,C]
{
    __shared__ _Float16 hbuf[2 * PARSTRIDE];   // [parity][limb][col][k]
    __shared__ int      slots[2][4] __attribute__((aligned(16)));
    __shared__ int      satf [2][4] __attribute__((aligned(16)));
    __shared__ unsigned Xs[16];
    __shared__ int      tmin;

    const int tid  = threadIdx.x;
    const int w    = tid >> 6;     // wave 0..3: rows [32w, 32w+32)
    const int lane = tid & 63;
    const int n    = lane & 15;    // MFMA col (batch)
    const int q    = lane >> 4;    // quad
    const int blk  = blockIdx.x;

    // ---- x prefetch into registers: row = tid>>4, slot = tid&15 ----
    // xr[j][m] = x[row][64*j + 4*slot + m]; 16 threads/row, float4-coalesced
    const int xrow = tid >> 4, xsl = tid & 15;
    const float* xp = &x[(size_t)(blk * 16 + xrow) * TLEN];
    f32x4 xr[8];
    #pragma unroll
    for (int j = 0; j < 8; ++j)
        xr[j] = *(const f32x4*)&xp[64 * j + 4 * xsl];

    // ---- W_hh fragments, two f16 limbs: A[m=lane&15][k=8q+j] per 32-k chunk ----
    f16x8 w1[2][4], w2[2][4];
    #pragma unroll
    for (int u = 0; u < 2; ++u) {
        #pragma unroll
        for (int kc = 0; kc < 4; ++kc) {
            const int row = 32 * w + 16 * u + n;
            const float* wp = &Whh[row * HDIM + 32 * kc + 8 * q];
            #pragma unroll
            for (int j = 0; j < 8; ++j) {
                const float v = wp[j];
                const _Float16 a = (_Float16)v;
                w1[u][kc][j] = a;
                w2[u][kc][j] = (_Float16)((v - (float)a) * 2048.0f);
            }
        }
    }
    // per-lane row constants: acc element (u,r) -> row 32w + 16u + 4q + r
    float wx[8], bb[8];
    #pragma unroll
    for (int u = 0; u < 2; ++u)
        #pragma unroll
        for (int r = 0; r < 4; ++r) {
            const int row = 32 * w + 16 * u + 4 * q + r;
            wx[4 * u + r] = Whx[row];
            bb[4 * u + r] = bh[row];
        }

    for (int i = tid; i < 2 * PARSTRIDE; i += 256) hbuf[i] = (_Float16)0.0f;
    if (tid < 4) { slots[0][tid] = 1; slots[1][tid] = 0;
                   satf[0][tid] = 0;  satf[1][tid] = 0; }
    __syncthreads();

    float accWh[8], h_prev[8], hv[8];
    #pragma unroll
    for (int i = 0; i < 8; ++i) { accWh[i] = 0.0f; h_prev[i] = 0.0f; }
    int p = 0;                     // parity of buffer holding current h
    bool force_step = false;

    const float* xcol = &x[(size_t)(blk * 16 + n) * TLEN];

    auto writeLimbs = [&](int par) {
        #pragma unroll
        for (int u = 0; u < 2; ++u) {
            PK4 p1, p2;
            #pragma unroll
            for (int r = 0; r < 4; ++r) {
                const float v = hv[4 * u + r];
                const _Float16 hh = (_Float16)v;
                p1.h[r] = hh;
                p2.h[r] = (_Float16)((v - (float)hh) * 2048.0f);
            }
            const int kb = 32 * w + 16 * u + 4 * q;
            *(uint2*)&hbuf[par * PARSTRIDE +              n * HS + kb] = p1.u;
            *(uint2*)&hbuf[par * PARSTRIDE + LIMBSTRIDE + n * HS + kb] = p2.u;
        }
    };

    int t = 0;
    while (t < TLEN) {
        const int4 sv = *(const int4*)&slots[t & 1][0];
        const int4 ss = *(const int4*)&satf[t & 1][0];
        const bool heavy  = (sv.x | sv.y | sv.z | sv.w) != 0;
        const bool allsat = (ss.x & ss.y & ss.z & ss.w) != 0;

        if (!force_step && !heavy && allsat) {
            // ---- stable: h frozen at exact +-1, accWh current. Skip ahead. ----
            if (tid < 16) Xs[tid] = 0x7f800000u;                  // +inf bits
            if (tid < 4)  { slots[0][tid] = 0; slots[1][tid] = 0; }
            if (tid == 0) tmin = TLEN;
            float m8 = 3.0e38f;
            #pragma unroll
            for (int i = 0; i < 8; ++i) {
                const float c  = accWh[i] + bb[i];
                const float mi = (c * h_prev[i] - 10.5f) / fmaxf(fabsf(wx[i]), 1e-30f);
                m8 = fminf(m8, mi);
            }
            m8 = fmaxf(m8, 0.0f);                                 // nonneg: uint order ok
            __syncthreads();
            atomicMin(&Xs[n], __float_as_uint(m8));
            __syncthreads();
            // branchless scan of the register copy of x
            const float Xc = __uint_as_float(Xs[xrow]);
            int idx = TLEN;
            #pragma unroll
            for (int j = 0; j < 8; ++j)
                #pragma unroll
                for (int m = 0; m < 4; ++m) {
                    const int vt = 64 * j + 4 * xsl + m;
                    const bool viol = (fabsf(xr[j][m]) >= Xc) && (vt >= t);
                    idx = viol ? min(idx, vt) : idx;
                }
            if (idx < TLEN) atomicMin(&tmin, idx);                // ~never taken
            __syncthreads();
            const int tv = tmin;
            if (tv >= TLEN) break;                 // identity to the end
            t = tv;                                // steps [t, tv) are identity
            force_step = true;                     // run a real (light) step at tv
            continue;
        }
        force_step = false;

        const float xt = xcol[t];

        if (heavy) {
            const _Float16* hb = &hbuf[p * PARSTRIDE];
            f16x8 b1[4], b2[4];
            #pragma unroll
            for (int kc = 0; kc < 4; ++kc) {
                b1[kc] = *(const f16x8*)&hb[             n * HS + 32 * kc + 8 * q];
                b2[kc] = *(const f16x8*)&hb[LIMBSTRIDE + n * HS + 32 * kc + 8 * q];
            }
            #pragma unroll
            for (int u = 0; u < 2; ++u) {
                f32x4 a0 = {0.0f, 0.0f, 0.0f, 0.0f};
                f32x4 a1 = {0.0f, 0.0f, 0.0f, 0.0f};
                #pragma unroll
                for (int kc = 0; kc < 4; ++kc) {
                    a0 = __builtin_amdgcn_mfma_f32_16x16x32_f16(w1[u][kc], b1[kc], a0, 0, 0, 0);
                    a1 = __builtin_amdgcn_mfma_f32_16x16x32_f16(w1[u][kc], b2[kc], a1, 0, 0, 0);
                    a1 = __builtin_amdgcn_mfma_f32_16x16x32_f16(w2[u][kc], b1[kc], a1, 0, 0, 0);
                }
                #pragma unroll
                for (int r = 0; r < 4; ++r)
                    accWh[4 * u + r] = fmaf(a1[r], 0x1p-11f, a0[r]);
            }
        }

        float pre[8];
        #pragma unroll
        for (int i = 0; i < 8; ++i)
            pre[i] = accWh[i] + fmaf(wx[i], xt, bb[i]);

        bool sat = true;
        #pragma unroll
        for (int i = 0; i < 8; ++i) sat = sat && (fabsf(pre[i]) > 10.0f);
        const bool wave_sat = (__ballot(sat) == ~0ull);
        if (wave_sat) {
            #pragma unroll
            for (int i = 0; i < 8; ++i) hv[i] = copysignf(1.0f, pre[i]);
        } else {
            #pragma unroll
            for (int i = 0; i < 8; ++i) hv[i] = tanh_fast(pre[i]);
        }

        bool eq = true;
        #pragma unroll
        for (int i = 0; i < 8; ++i) eq = eq && (hv[i] == h_prev[i]);
        const bool wave_changed = (__ballot(eq) != ~0ull);
        #pragma unroll
        for (int i = 0; i < 8; ++i) h_prev[i] = hv[i];

        if (heavy) {
            writeLimbs(p ^ 1);
            p ^= 1;
        } else if (wave_changed) {
            writeLimbs(0);                 // keep both parities current
            writeLimbs(1);
        }
        if (lane == 0) {
            slots[(t + 1) & 1][w] = wave_changed ? 1 : 0;
            satf [(t + 1) & 1][w] = wave_sat ? 1 : 0;
        }
        __syncthreads();
        ++t;
    }

    // ---- projection: out[b][co] = sum_i Wph[co][i]*h_T[i][b] + bp[co] ----
    if (tid < 16 * NCLS) {
        const int c  = tid / NCLS;
        const int co = tid - c * NCLS;
        const _Float16* h1 = &hbuf[p * PARSTRIDE +              c * HS];
        const _Float16* h2 = &hbuf[p * PARSTRIDE + LIMBSTRIDE + c * HS];
        float s = bp[co];
        #pragma unroll 8
        for (int i = 0; i < HDIM; ++i)
            s = fmaf(Wph[co * HDIM + i],
                     (float)h1[i] + (float)h2[i] * (1.0f / 2048.0f), s);
        out[((size_t)blk * 16 + c) * NCLS + co] = s;
    }
}

extern "C" void kernel_launch(void* const* d_in, const int* in_sizes, int n_in,
                              void* d_out, int out_size, void* d_ws, size_t ws_size,
                              hipStream_t stream) {
    const float* x   = (const float*)d_in[0];  // [4096,512]
    const float* Whx = (const float*)d_in[1];  // [128,1]
    const float* Whh = (const float*)d_in[2];  // [128,128]
    const float* Wph = (const float*)d_in[3];  // [10,128]
    const float* bh  = (const float*)d_in[4];  // [128,1]
    const float* bp  = (const float*)d_in[5];  // [10,1]
    float* out = (float*)d_out;                // [4096,10]

    rnn_kernel<<<dim3(256), dim3(256), 0, stream>>>(x, Whx, Whh, Wph, bh, bp, out);
}